// Round 3
// baseline (110.378 us; speedup 1.0000x reference)
//
#include <hip/hip_runtime.h>
#include <hip/hip_bf16.h>
#include <math.h>

// Problem constants (from reference)
#define BB 32
#define CC 30
#define RR 196
#define DD 256
#define KK 20
#define GG 14            // sqrt(RR)
#define CONF_ 0.5f
#define IOU_THR_ 0.3f

constexpr int NROWS = BB * CC * RR;          // 188160
constexpr int COORDS_OFF = 0;                // (B,C,K,4) = 76800
constexpr int PROBS_OFF  = BB * CC * KK * 4; // 76800
constexpr int KEEP_OFF   = PROBS_OFF + BB * CC * KK;  // 96000
constexpr int PRES_OFF   = KEEP_OFF + BB * CC * KK;   // 115200

__device__ __forceinline__ float dot4(float4 a, float4 b) {
    return a.x * b.x + a.y * b.y + a.z * b.z + a.w * b.w;
}

// ---------------------------------------------------------------------------
// Fully fused: one block (4 waves) per (b,c).
// Phase 1: stream the 196 rows once; compute presence logit AND all 4 coord
//          dots per row (4 extra dots = pure VALU, zero extra HBM).
//          Wave w owns rows [w*48, w*48+48): 3 rows/lane, 4 lanes/row,
//          interleaved quarters (wi = q + 4t) so each row's 4 lanes cover a
//          contiguous 64B segment per instruction. Wave 3 also does the
//          4-row tail (192..195). Results -> LDS (+ presence -> d_out).
// Phase 2: wave 0 only: top-K argmax over LDS logits, box assembly from LDS
//          coords, lockstep NMS via shuffles, outputs. No second launch, no
//          logits round-trip, no gathered re-read.
// ---------------------------------------------------------------------------
__global__ __launch_bounds__(256) void fused_bbox_kernel(
    const float4* __restrict__ lf,        // NROWS * 64 float4
    const float*  __restrict__ W_coords,  // 4 x 256
    const float*  __restrict__ b_coords,  // 4
    const float*  __restrict__ W_pres,    // 256
    const float*  __restrict__ b_pres,    // 1
    float* __restrict__ coords_out,
    float* __restrict__ probs_out,
    float* __restrict__ keep_out,
    float* __restrict__ presence_out)
{
    const int bc   = blockIdx.x;
    const int tid  = threadIdx.x;
    const int wv   = tid >> 6;
    const int lane = tid & 63;
    const int sub  = lane >> 2;   // row within 16-row group
    const int q    = lane & 3;    // quarter selector

    __shared__ float  s_logit[RR];
    __shared__ float4 s_coord[RR];

    const float4* __restrict__ Wp4 = reinterpret_cast<const float4*>(W_pres);
    const float4* __restrict__ Wc4 = reinterpret_cast<const float4*>(W_coords);
    const float  bp   = b_pres[0];
    const size_t tile = (size_t)bc * RR;

    // ---- Phase 1 main: wave wv -> rows wv*48 + {sub, sub+16, sub+32} ----
    {
        const int r0 = wv * 48 + sub;
        const float4* __restrict__ p0 = lf + (tile + r0     ) * 64;
        const float4* __restrict__ p1 = lf + (tile + r0 + 16) * 64;
        const float4* __restrict__ p2 = lf + (tile + r0 + 32) * 64;

        float a0[5] = {0,0,0,0,0}, a1[5] = {0,0,0,0,0}, a2[5] = {0,0,0,0,0};
        #pragma unroll
        for (int t = 0; t < 16; ++t) {
            const int wi = q + 4 * t;
            const float4 wp = Wp4[wi];
            const float4 w0 = Wc4[wi];
            const float4 w1 = Wc4[64  + wi];
            const float4 w2 = Wc4[128 + wi];
            const float4 w3 = Wc4[192 + wi];
            const float4 xa = p0[wi];
            const float4 xb = p1[wi];
            const float4 xc = p2[wi];
            a0[0] += dot4(xa, wp); a0[1] += dot4(xa, w0); a0[2] += dot4(xa, w1);
            a0[3] += dot4(xa, w2); a0[4] += dot4(xa, w3);
            a1[0] += dot4(xb, wp); a1[1] += dot4(xb, w0); a1[2] += dot4(xb, w1);
            a1[3] += dot4(xb, w2); a1[4] += dot4(xb, w3);
            a2[0] += dot4(xc, wp); a2[1] += dot4(xc, w0); a2[2] += dot4(xc, w1);
            a2[3] += dot4(xc, w2); a2[4] += dot4(xc, w3);
        }

        float* accs[3] = {a0, a1, a2};
        #pragma unroll
        for (int j = 0; j < 3; ++j) {
            float* a = accs[j];
            const int r = r0 + 16 * j;
            #pragma unroll
            for (int o = 0; o < 5; ++o) {
                float v = a[o];
                v += __shfl_xor(v, 1);
                v += __shfl_xor(v, 2);
                a[o] = v;
            }
            if (q == 0) {
                const float lg = a[0] + bp;
                s_logit[r] = lg;
                presence_out[tile + r] = lg;
                s_coord[r] = make_float4(a[1], a[2], a[3], a[4]);
            }
        }
    }

    // ---- Phase 1 tail: rows 192..195 on wave 3 (4 lanes/row) ----
    if (wv == 3) {
        const int  r  = 192 + sub;
        const bool ok = (sub < 4);
        float a[5] = {0,0,0,0,0};
        if (ok) {
            const float4* __restrict__ rp = lf + (tile + r) * 64;
            #pragma unroll
            for (int t = 0; t < 16; ++t) {
                const int wi = q + 4 * t;
                const float4 x  = rp[wi];
                const float4 wp = Wp4[wi];
                const float4 w0 = Wc4[wi];
                const float4 w1 = Wc4[64  + wi];
                const float4 w2 = Wc4[128 + wi];
                const float4 w3 = Wc4[192 + wi];
                a[0] += dot4(x, wp); a[1] += dot4(x, w0); a[2] += dot4(x, w1);
                a[3] += dot4(x, w2); a[4] += dot4(x, w3);
            }
        }
        #pragma unroll
        for (int o = 0; o < 5; ++o) {
            float v = a[o];
            v += __shfl_xor(v, 1);
            v += __shfl_xor(v, 2);
            a[o] = v;
        }
        if (ok && q == 0) {
            const float lg = a[0] + bp;
            s_logit[r] = lg;
            presence_out[tile + r] = lg;
            s_coord[r] = make_float4(a[1], a[2], a[3], a[4]);
        }
    }

    __syncthreads();
    if (wv != 0) return;

    // ---- Phase 2: top-K argmax over logits (monotone sigmoid) ----
    float v[4]; int id[4];
    #pragma unroll
    for (int t = 0; t < 4; ++t) {
        const int r = lane + 64 * t;
        id[t] = r;
        v[t]  = (r < RR) ? s_logit[r] : -1e30f;
    }

    float myv = -1e30f; int myi = 0;
    for (int k = 0; k < KK; ++k) {
        float bv = v[0]; int bi = id[0];
        #pragma unroll
        for (int t = 1; t < 4; ++t)
            if (v[t] > bv || (v[t] == bv && id[t] < bi)) { bv = v[t]; bi = id[t]; }
        #pragma unroll
        for (int off = 32; off; off >>= 1) {
            const float ov = __shfl_xor(bv, off);
            const int   oi = __shfl_xor(bi, off);
            if (ov > bv || (ov == bv && oi < bi)) { bv = ov; bi = oi; }
        }
        #pragma unroll
        for (int t = 0; t < 4; ++t)
            if (id[t] == bi) v[t] = -1e30f;
        if (lane == k) { myv = bv; myi = bi; }
    }

    // ---- box assembly ----
    float x1 = 0.f, y1 = 0.f, x2 = 0.f, y2 = 0.f, area = 0.f, prob = 0.f;
    int kp = 0;
    if (lane < KK) {
        const float4 c = s_coord[myi];
        const int   ix = myi % GG, iy = myi / GG;
        const float cx = (ix + 0.5f) / (float)GG;
        const float cy = (iy + 0.5f) / (float)GG;
        x1 = c.x + b_coords[0] + cx;
        y1 = c.y + b_coords[1] + cy;
        x2 = c.z + b_coords[2] + cx;
        y2 = c.w + b_coords[3] + cy;
        area = fmaxf(x2 - x1, 0.f) * fmaxf(y2 - y1, 0.f);
        prob = 1.f / (1.f + expf(-myv));
        kp   = (prob > CONF_) ? 1 : 0;
    }

    // ---- NMS: lane j owns box j, lockstep over i ----
    for (int i = 0; i < KK; ++i) {
        const int   ki  = __shfl(kp, i);
        const float bx1 = __shfl(x1, i), by1 = __shfl(y1, i);
        const float bx2 = __shfl(x2, i), by2 = __shfl(y2, i);
        const float ai  = __shfl(area, i);
        if (lane > i && lane < KK && ki) {
            const float xx1 = fmaxf(x1, bx1), yy1 = fmaxf(y1, by1);
            const float xx2 = fminf(x2, bx2), yy2 = fminf(y2, by2);
            const float inter = fmaxf(xx2 - xx1, 0.f) * fmaxf(yy2 - yy1, 0.f);
            const float uni   = area + ai - inter;
            const float iou   = inter / fmaxf(uni, 1e-9f);
            if (iou > IOU_THR_) kp = 0;
        }
    }

    // ---- outputs ----
    if (lane < KK) {
        const size_t base = (size_t)bc * KK + lane;
        const float  kf   = kp ? 1.f : 0.f;
        coords_out[base * 4 + 0] = x1 * kf;
        coords_out[base * 4 + 1] = y1 * kf;
        coords_out[base * 4 + 2] = x2 * kf;
        coords_out[base * 4 + 3] = y2 * kf;
        probs_out[base] = prob * kf;
        keep_out[base]  = kf;
    }
}

extern "C" void kernel_launch(void* const* d_in, const int* in_sizes, int n_in,
                              void* d_out, int out_size, void* d_ws, size_t ws_size,
                              hipStream_t stream) {
    const float* lf       = (const float*)d_in[0];
    const float* W_coords = (const float*)d_in[1];
    const float* b_coords = (const float*)d_in[2];
    const float* W_pres   = (const float*)d_in[3];
    const float* b_pres   = (const float*)d_in[4];

    float* out          = (float*)d_out;
    float* coords_out   = out + COORDS_OFF;
    float* probs_out    = out + PROBS_OFF;
    float* keep_out     = out + KEEP_OFF;
    float* presence_out = out + PRES_OFF;

    // One block per (b,c): 960 blocks x 256 threads = 15 waves/CU, all resident.
    fused_bbox_kernel<<<BB * CC, 256, 0, stream>>>(
        (const float4*)lf, W_coords, b_coords, W_pres, b_pres,
        coords_out, probs_out, keep_out, presence_out);
}

// Round 4
// 57.208 us; speedup vs baseline: 1.9294x; 1.9294x over previous
//
#include <hip/hip_runtime.h>
#include <hip/hip_bf16.h>
#include <math.h>

// Problem constants (from reference)
#define BB 32
#define CC 30
#define RR 196
#define DD 256
#define KK 20
#define GG 14            // sqrt(RR)
#define CONF_ 0.5f
#define IOU_THR_ 0.3f

constexpr int NROWS = BB * CC * RR;          // 188160
constexpr int COORDS_OFF = 0;                // (B,C,K,4) = 76800
constexpr int PROBS_OFF  = BB * CC * KK * 4; // 76800
constexpr int KEEP_OFF   = PROBS_OFF + BB * CC * KK;  // 96000
constexpr int PRES_OFF   = KEEP_OFF + BB * CC * KK;   // 115200

__device__ __forceinline__ float dot4(float4 a, float4 b) {
    return a.x * b.x + a.y * b.y + a.z * b.z + a.w * b.w;
}

// ---------------------------------------------------------------------------
// Stage 1: presence logit + full box (bias + grid center applied) per row.
// R2's proven lean shape: 16 rows/wave, 4 lanes/row, 16 float4 per lane,
// but with 5 accumulators (presence + 4 coord dots). #pragma unroll 4 caps
// live ranges so VGPR stays low (R3 lesson: the 248-VGPR balloon killed
// occupancy). Weights are 5 KB, L1-resident. Zero extra HBM vs R2.
// ---------------------------------------------------------------------------
__global__ __launch_bounds__(256) void mlp_kernel(
    const float4* __restrict__ lf,        // NROWS * 64 float4
    const float*  __restrict__ W_coords,  // 4 x 256
    const float*  __restrict__ b_coords,  // 4
    const float*  __restrict__ W_pres,    // 256
    const float*  __restrict__ b_pres,    // 1
    float*  __restrict__ presence_out,    // NROWS (d_out presence section)
    float4* __restrict__ boxes_ws)        // NROWS finished boxes (d_ws)
{
    const int lane = threadIdx.x & 63;
    const int wave = blockIdx.x * 4 + (threadIdx.x >> 6);
    const int sub  = lane >> 2;           // row within 16-row group
    const int q    = lane & 3;            // quarter-slot selector

    const int row = wave * 16 + sub;      // exact grid: always < NROWS
    const float4* __restrict__ rowp = lf + (size_t)row * 64 + q;
    const float4* __restrict__ Wp4  = reinterpret_cast<const float4*>(W_pres) + q;
    const float4* __restrict__ Wc4  = reinterpret_cast<const float4*>(W_coords) + q;

    float ap = 0.f, a0 = 0.f, a1 = 0.f, a2 = 0.f, a3 = 0.f;
    #pragma unroll 4
    for (int t = 0; t < 16; ++t) {
        const float4 x = rowp[4 * t];
        ap += dot4(x, Wp4[4 * t]);
        a0 += dot4(x, Wc4[4 * t]);
        a1 += dot4(x, Wc4[64 + 4 * t]);
        a2 += dot4(x, Wc4[128 + 4 * t]);
        a3 += dot4(x, Wc4[192 + 4 * t]);
    }
    ap += __shfl_xor(ap, 1); ap += __shfl_xor(ap, 2);
    a0 += __shfl_xor(a0, 1); a0 += __shfl_xor(a0, 2);
    a1 += __shfl_xor(a1, 1); a1 += __shfl_xor(a1, 2);
    a2 += __shfl_xor(a2, 1); a2 += __shfl_xor(a2, 2);
    a3 += __shfl_xor(a3, 1); a3 += __shfl_xor(a3, 2);

    if (q == 0) {
        presence_out[row] = ap + b_pres[0];
        const int   r  = row % RR;
        const int   ix = r % GG, iy = r / GG;
        const float cx = (ix + 0.5f) / (float)GG;
        const float cy = (iy + 0.5f) / (float)GG;
        boxes_ws[row] = make_float4(a0 + b_coords[0] + cx,
                                    a1 + b_coords[1] + cy,
                                    a2 + b_coords[2] + cx,
                                    a3 + b_coords[3] + cy);
    }
}

// ---------------------------------------------------------------------------
// Stage 2 (cheap): one wave per (b,c), 4 waves/block -> 240 blocks.
// top-K argmax on logits (sigmoid monotone), box read from d_ws, NMS, write.
// No lf access at all.
// ---------------------------------------------------------------------------
__global__ __launch_bounds__(256) void topk_nms_kernel(
    const float*  __restrict__ presence,  // NROWS logits (d_out section)
    const float4* __restrict__ boxes_ws,  // NROWS boxes (d_ws)
    const float*  __restrict__ presence_dummy_keepalive,
    float* __restrict__ coords_out,
    float* __restrict__ probs_out,
    float* __restrict__ keep_out)
{
    const int wv   = threadIdx.x >> 6;
    const int lane = threadIdx.x & 63;
    const int bc   = blockIdx.x * 4 + wv;

    // --- load the 196 logits: 4 per lane (padded) ---
    const float* pres = presence + (size_t)bc * RR;
    float v[4]; int id[4];
    #pragma unroll
    for (int t = 0; t < 4; ++t) {
        const int r = lane + 64 * t;
        id[t] = r;
        v[t]  = (r < RR) ? pres[r] : -1e30f;
    }

    // --- top-K: K sequential wave-argmax butterflies; lane k keeps k-th ---
    float myv = -1e30f; int myi = 0;
    for (int k = 0; k < KK; ++k) {
        float bv = v[0]; int bi = id[0];
        #pragma unroll
        for (int t = 1; t < 4; ++t)
            if (v[t] > bv || (v[t] == bv && id[t] < bi)) { bv = v[t]; bi = id[t]; }
        #pragma unroll
        for (int off = 32; off; off >>= 1) {
            const float ov = __shfl_xor(bv, off);
            const int   oi = __shfl_xor(bi, off);
            if (ov > bv || (ov == bv && oi < bi)) { bv = ov; bi = oi; }
        }
        #pragma unroll
        for (int t = 0; t < 4; ++t)
            if (id[t] == bi) v[t] = -1e30f;
        if (lane == k) { myv = bv; myi = bi; }
    }

    // --- box fetch + NMS state ---
    float x1 = 0.f, y1 = 0.f, x2 = 0.f, y2 = 0.f, area = 0.f, prob = 0.f;
    int kp = 0;
    if (lane < KK) {
        const float4 b = boxes_ws[(size_t)bc * RR + myi];
        x1 = b.x; y1 = b.y; x2 = b.z; y2 = b.w;
        area = fmaxf(x2 - x1, 0.f) * fmaxf(y2 - y1, 0.f);
        prob = 1.f / (1.f + expf(-myv));
        kp   = (prob > CONF_) ? 1 : 0;
    }
    for (int i = 0; i < KK; ++i) {
        const int   ki  = __shfl(kp, i);
        const float bx1 = __shfl(x1, i), by1 = __shfl(y1, i);
        const float bx2 = __shfl(x2, i), by2 = __shfl(y2, i);
        const float ai  = __shfl(area, i);
        if (lane > i && lane < KK && ki) {
            const float xx1 = fmaxf(x1, bx1), yy1 = fmaxf(y1, by1);
            const float xx2 = fminf(x2, bx2), yy2 = fminf(y2, by2);
            const float inter = fmaxf(xx2 - xx1, 0.f) * fmaxf(yy2 - yy1, 0.f);
            const float uni   = area + ai - inter;
            const float iou   = inter / fmaxf(uni, 1e-9f);
            if (iou > IOU_THR_) kp = 0;
        }
    }

    if (lane < KK) {
        const size_t base = (size_t)bc * KK + lane;
        const float  kf   = kp ? 1.f : 0.f;
        coords_out[base * 4 + 0] = x1 * kf;
        coords_out[base * 4 + 1] = y1 * kf;
        coords_out[base * 4 + 2] = x2 * kf;
        coords_out[base * 4 + 3] = y2 * kf;
        probs_out[base] = prob * kf;
        keep_out[base]  = kf;
    }
}

// ---------------------------------------------------------------------------
// Fallback stage 2 (only if ws_size too small): R2's recompute-from-lf path.
// ---------------------------------------------------------------------------
__global__ __launch_bounds__(64) void topk_nms_recompute_kernel(
    const float4* __restrict__ lf,
    const float*  __restrict__ W_coords,
    const float*  __restrict__ b_coords,
    const float*  __restrict__ presence,
    float* __restrict__ coords_out,
    float* __restrict__ probs_out,
    float* __restrict__ keep_out)
{
    const int bc   = blockIdx.x;
    const int lane = threadIdx.x;

    __shared__ float s_topv[KK];
    __shared__ int   s_topi[KK];
    __shared__ float s_box[KK][4];

    const float* pres = presence + (size_t)bc * RR;
    float v[4]; int id[4];
    #pragma unroll
    for (int t = 0; t < 4; ++t) {
        const int r = lane + 64 * t;
        id[t] = r;
        v[t]  = (r < RR) ? pres[r] : -1e30f;
    }
    for (int k = 0; k < KK; ++k) {
        float bv = v[0]; int bi = id[0];
        #pragma unroll
        for (int t = 1; t < 4; ++t)
            if (v[t] > bv || (v[t] == bv && id[t] < bi)) { bv = v[t]; bi = id[t]; }
        #pragma unroll
        for (int off = 32; off; off >>= 1) {
            const float ov = __shfl_xor(bv, off);
            const int   oi = __shfl_xor(bi, off);
            if (ov > bv || (ov == bv && oi < bi)) { bv = ov; bi = oi; }
        }
        #pragma unroll
        for (int t = 0; t < 4; ++t)
            if (id[t] == bi) v[t] = -1e30f;
        if (lane == 0) { s_topv[k] = bv; s_topi[k] = bi; }
    }
    __syncthreads();

    const int g  = lane >> 4;
    const int sl = lane & 15;
    float4 wc[4][4];
    #pragma unroll
    for (int o = 0; o < 4; ++o)
        #pragma unroll
        for (int t = 0; t < 4; ++t)
            wc[o][t] = reinterpret_cast<const float4*>(W_coords + o * DD)[sl + 16 * t];

    #pragma unroll
    for (int it = 0; it < KK / 4; ++it) {
        const int k   = it * 4 + g;
        const int row = s_topi[k];
        const float4* __restrict__ rp = lf + ((size_t)bc * RR + row) * 64 + sl;
        float acc[4] = {0.f, 0.f, 0.f, 0.f};
        #pragma unroll
        for (int t = 0; t < 4; ++t) {
            const float4 x = rp[16 * t];
            #pragma unroll
            for (int o = 0; o < 4; ++o)
                acc[o] += x.x * wc[o][t].x + x.y * wc[o][t].y
                        + x.z * wc[o][t].z + x.w * wc[o][t].w;
        }
        #pragma unroll
        for (int off = 8; off; off >>= 1) {
            #pragma unroll
            for (int o = 0; o < 4; ++o) acc[o] += __shfl_xor(acc[o], off);
        }
        if (sl == 0) {
            const int   ix = row % GG, iy = row / GG;
            const float cx = (ix + 0.5f) / (float)GG;
            const float cy = (iy + 0.5f) / (float)GG;
            s_box[k][0] = acc[0] + b_coords[0] + cx;
            s_box[k][1] = acc[1] + b_coords[1] + cy;
            s_box[k][2] = acc[2] + b_coords[2] + cx;
            s_box[k][3] = acc[3] + b_coords[3] + cy;
        }
    }
    __syncthreads();

    float x1 = 0.f, y1 = 0.f, x2 = 0.f, y2 = 0.f, area = 0.f, prob = 0.f;
    int kp = 0;
    if (lane < KK) {
        x1 = s_box[lane][0]; y1 = s_box[lane][1];
        x2 = s_box[lane][2]; y2 = s_box[lane][3];
        area = fmaxf(x2 - x1, 0.f) * fmaxf(y2 - y1, 0.f);
        prob = 1.f / (1.f + expf(-s_topv[lane]));
        kp = (prob > CONF_) ? 1 : 0;
    }
    for (int i = 0; i < KK; ++i) {
        const int   ki  = __shfl(kp, i);
        const float bx1 = __shfl(x1, i), by1 = __shfl(y1, i);
        const float bx2 = __shfl(x2, i), by2 = __shfl(y2, i);
        const float ai  = __shfl(area, i);
        if (lane > i && lane < KK && ki) {
            const float xx1 = fmaxf(x1, bx1), yy1 = fmaxf(y1, by1);
            const float xx2 = fminf(x2, bx2), yy2 = fminf(y2, by2);
            const float inter = fmaxf(xx2 - xx1, 0.f) * fmaxf(yy2 - yy1, 0.f);
            const float uni   = area + ai - inter;
            const float iou   = inter / fmaxf(uni, 1e-9f);
            if (iou > IOU_THR_) kp = 0;
        }
    }
    if (lane < KK) {
        const size_t base = (size_t)bc * KK + lane;
        const float  kf   = kp ? 1.f : 0.f;
        coords_out[base * 4 + 0] = x1 * kf;
        coords_out[base * 4 + 1] = y1 * kf;
        coords_out[base * 4 + 2] = x2 * kf;
        coords_out[base * 4 + 3] = y2 * kf;
        probs_out[base] = prob * kf;
        keep_out[base]  = kf;
    }
}

// Stage-1 kernel without the ws write, for the fallback path.
__global__ __launch_bounds__(256) void presence_only_kernel(
    const float4* __restrict__ lf,
    const float*  __restrict__ W_pres,
    const float*  __restrict__ b_pres,
    float* __restrict__ presence_out)
{
    const int lane = threadIdx.x & 63;
    const int wave = blockIdx.x * 4 + (threadIdx.x >> 6);
    const int sub  = lane >> 2;
    const int q    = lane & 3;
    const int row  = wave * 16 + sub;
    const float4* __restrict__ rowp = lf + (size_t)row * 64 + q;
    const float4* __restrict__ wp   = reinterpret_cast<const float4*>(W_pres) + q;

    float p = 0.f;
    #pragma unroll
    for (int t = 0; t < 16; ++t) {
        const float4 x = rowp[4 * t];
        const float4 w = wp[4 * t];
        p += dot4(x, w);
    }
    p += __shfl_xor(p, 1);
    p += __shfl_xor(p, 2);
    if (q == 0) presence_out[row] = p + b_pres[0];
}

extern "C" void kernel_launch(void* const* d_in, const int* in_sizes, int n_in,
                              void* d_out, int out_size, void* d_ws, size_t ws_size,
                              hipStream_t stream) {
    const float* lf       = (const float*)d_in[0];
    const float* W_coords = (const float*)d_in[1];
    const float* b_coords = (const float*)d_in[2];
    const float* W_pres   = (const float*)d_in[3];
    const float* b_pres   = (const float*)d_in[4];

    float* out          = (float*)d_out;
    float* coords_out   = out + COORDS_OFF;
    float* probs_out    = out + PROBS_OFF;
    float* keep_out     = out + KEEP_OFF;
    float* presence_out = out + PRES_OFF;

    const size_t ws_needed = (size_t)NROWS * 4 * sizeof(float);

    if (ws_size >= ws_needed) {
        float4* boxes_ws = (float4*)d_ws;
        // Stage 1: 2940 blocks x 4 waves, 16 rows/wave = exactly NROWS rows.
        mlp_kernel<<<NROWS / 64, 256, 0, stream>>>(
            (const float4*)lf, W_coords, b_coords, W_pres, b_pres,
            presence_out, boxes_ws);
        // Stage 2: 240 blocks x 4 waves, one wave per (b,c).
        topk_nms_kernel<<<BB * CC / 4, 256, 0, stream>>>(
            presence_out, boxes_ws, presence_out,
            coords_out, probs_out, keep_out);
    } else {
        presence_only_kernel<<<NROWS / 64, 256, 0, stream>>>(
            (const float4*)lf, W_pres, b_pres, presence_out);
        topk_nms_recompute_kernel<<<BB * CC, 64, 0, stream>>>(
            (const float4*)lf, W_coords, b_coords, presence_out,
            coords_out, probs_out, keep_out);
    }
}

// Round 5
// 51.463 us; speedup vs baseline: 2.1448x; 1.1116x over previous
//
#include <hip/hip_runtime.h>
#include <hip/hip_bf16.h>
#include <math.h>

// Problem constants (from reference)
#define BB 32
#define CC 30
#define RR 196
#define DD 256
#define KK 20
#define GG 14            // sqrt(RR)
#define CONF_ 0.5f
#define IOU_THR_ 0.3f

constexpr int NROWS = BB * CC * RR;          // 188160
constexpr int COORDS_OFF = 0;                // (B,C,K,4) = 76800
constexpr int PROBS_OFF  = BB * CC * KK * 4; // 76800
constexpr int KEEP_OFF   = PROBS_OFF + BB * CC * KK;  // 96000
constexpr int PRES_OFF   = KEEP_OFF + BB * CC * KK;   // 115200

__device__ __forceinline__ float dot4(float4 a, float4 b) {
    return a.x * b.x + a.y * b.y + a.z * b.z + a.w * b.w;
}

// ---------------------------------------------------------------------------
// Stage 1: presence logit + finished box per row, ONE pass over lf.
// Layout: 16 lanes/row, 4 rows per wave-granule, 4 taps/lane (o + 16t).
// ALL weights (5 streams x 4 taps = 20 float4 = 80 VGPR) are loaded ONCE and
// held in registers -> the streaming loop has exactly ONE load instruction
// per 1 KiB of lf (R3 lesson: per-tap weight loads saturate L1 return BW at
// ~10 B/cy/CU, below the ~23 B/cy needed for 6 TB/s).
// Grid-stride, 2048 blocks = 8192 waves resident -> 5.74 granules/wave,
// ~4% imbalance (R1/R3 lesson: 1.44-round launch wasted ~28%).
// ---------------------------------------------------------------------------
__global__ __launch_bounds__(256, 4) void mlp_kernel(
    const float4* __restrict__ lf,        // NROWS * 64 float4
    const float*  __restrict__ W_coords,  // 4 x 256
    const float*  __restrict__ b_coords,  // 4
    const float*  __restrict__ W_pres,    // 256
    const float*  __restrict__ b_pres,    // 1
    float*  __restrict__ presence_out,    // NROWS (d_out presence section)
    float4* __restrict__ boxes_ws)        // NROWS finished boxes (d_ws)
{
    const int lane = threadIdx.x & 63;
    const int wave = blockIdx.x * 4 + (threadIdx.x >> 6);
    const int gr   = lane >> 4;           // row slot within granule (0..3)
    const int o    = lane & 15;           // sub-lane within row

    const float4* __restrict__ Wp4 = reinterpret_cast<const float4*>(W_pres);
    const float4* __restrict__ Wc4 = reinterpret_cast<const float4*>(W_coords);

    // Weights in registers, loaded once (L1), loop-invariant.
    float4 wp[4], w0[4], w1[4], w2[4], w3[4];
    #pragma unroll
    for (int t = 0; t < 4; ++t) {
        wp[t] = Wp4[o + 16 * t];
        w0[t] = Wc4[      o + 16 * t];
        w1[t] = Wc4[ 64 + o + 16 * t];
        w2[t] = Wc4[128 + o + 16 * t];
        w3[t] = Wc4[192 + o + 16 * t];
    }
    const float bp  = b_pres[0];
    const float bc0 = b_coords[0], bc1 = b_coords[1];
    const float bc2 = b_coords[2], bc3 = b_coords[3];

    constexpr int NGRAN = NROWS / 4;      // 47040 granules of 4 rows
    const int nwave = 2048 * 4;           // 8192 waves

    for (int g = wave; g < NGRAN; g += nwave) {
        const int row = g * 4 + gr;
        const float4* __restrict__ rp = lf + (size_t)row * 64;

        float ap = 0.f, a0 = 0.f, a1 = 0.f, a2 = 0.f, a3 = 0.f;
        #pragma unroll
        for (int t = 0; t < 4; ++t) {
            const float4 x = rp[o + 16 * t];
            ap += dot4(x, wp[t]);
            a0 += dot4(x, w0[t]);
            a1 += dot4(x, w1[t]);
            a2 += dot4(x, w2[t]);
            a3 += dot4(x, w3[t]);
        }
        // reduce across the 16 lanes of this row
        #pragma unroll
        for (int off = 1; off < 16; off <<= 1) {
            ap += __shfl_xor(ap, off);
            a0 += __shfl_xor(a0, off);
            a1 += __shfl_xor(a1, off);
            a2 += __shfl_xor(a2, off);
            a3 += __shfl_xor(a3, off);
        }
        if (o == 0) {
            presence_out[row] = ap + bp;
            const int   r  = row % RR;
            const int   ix = r % GG, iy = r / GG;
            const float cx = (ix + 0.5f) / (float)GG;
            const float cy = (iy + 0.5f) / (float)GG;
            boxes_ws[row] = make_float4(a0 + bc0 + cx, a1 + bc1 + cy,
                                        a2 + bc2 + cx, a3 + bc3 + cy);
        }
    }
}

// ---------------------------------------------------------------------------
// Stage 2 (cheap): one wave per (b,c), 4 waves/block -> 240 blocks.
// top-K argmax on logits (sigmoid monotone), box read from d_ws, NMS, write.
// No lf access at all.
// ---------------------------------------------------------------------------
__global__ __launch_bounds__(256) void topk_nms_kernel(
    const float*  __restrict__ presence,  // NROWS logits (d_out section)
    const float4* __restrict__ boxes_ws,  // NROWS boxes (d_ws)
    float* __restrict__ coords_out,
    float* __restrict__ probs_out,
    float* __restrict__ keep_out)
{
    const int wv   = threadIdx.x >> 6;
    const int lane = threadIdx.x & 63;
    const int bc   = blockIdx.x * 4 + wv;

    const float* pres = presence + (size_t)bc * RR;
    float v[4]; int id[4];
    #pragma unroll
    for (int t = 0; t < 4; ++t) {
        const int r = lane + 64 * t;
        id[t] = r;
        v[t]  = (r < RR) ? pres[r] : -1e30f;
    }

    // top-K: K sequential wave-argmax butterflies; lane k keeps the k-th hit
    float myv = -1e30f; int myi = 0;
    for (int k = 0; k < KK; ++k) {
        float bv = v[0]; int bi = id[0];
        #pragma unroll
        for (int t = 1; t < 4; ++t)
            if (v[t] > bv || (v[t] == bv && id[t] < bi)) { bv = v[t]; bi = id[t]; }
        #pragma unroll
        for (int off = 32; off; off >>= 1) {
            const float ov = __shfl_xor(bv, off);
            const int   oi = __shfl_xor(bi, off);
            if (ov > bv || (ov == bv && oi < bi)) { bv = ov; bi = oi; }
        }
        #pragma unroll
        for (int t = 0; t < 4; ++t)
            if (id[t] == bi) v[t] = -1e30f;
        if (lane == k) { myv = bv; myi = bi; }
    }

    // box fetch + NMS state
    float x1 = 0.f, y1 = 0.f, x2 = 0.f, y2 = 0.f, area = 0.f, prob = 0.f;
    int kp = 0;
    if (lane < KK) {
        const float4 b = boxes_ws[(size_t)bc * RR + myi];
        x1 = b.x; y1 = b.y; x2 = b.z; y2 = b.w;
        area = fmaxf(x2 - x1, 0.f) * fmaxf(y2 - y1, 0.f);
        prob = 1.f / (1.f + expf(-myv));
        kp   = (prob > CONF_) ? 1 : 0;
    }
    for (int i = 0; i < KK; ++i) {
        const int   ki  = __shfl(kp, i);
        const float bx1 = __shfl(x1, i), by1 = __shfl(y1, i);
        const float bx2 = __shfl(x2, i), by2 = __shfl(y2, i);
        const float ai  = __shfl(area, i);
        if (lane > i && lane < KK && ki) {
            const float xx1 = fmaxf(x1, bx1), yy1 = fmaxf(y1, by1);
            const float xx2 = fminf(x2, bx2), yy2 = fminf(y2, by2);
            const float inter = fmaxf(xx2 - xx1, 0.f) * fmaxf(yy2 - yy1, 0.f);
            const float uni   = area + ai - inter;
            const float iou   = inter / fmaxf(uni, 1e-9f);
            if (iou > IOU_THR_) kp = 0;
        }
    }

    if (lane < KK) {
        const size_t base = (size_t)bc * KK + lane;
        const float  kf   = kp ? 1.f : 0.f;
        coords_out[base * 4 + 0] = x1 * kf;
        coords_out[base * 4 + 1] = y1 * kf;
        coords_out[base * 4 + 2] = x2 * kf;
        coords_out[base * 4 + 3] = y2 * kf;
        probs_out[base] = prob * kf;
        keep_out[base]  = kf;
    }
}

// ---------------------------------------------------------------------------
// Fallback (ws too small — not expected): R1-style presence + recompute.
// ---------------------------------------------------------------------------
__global__ __launch_bounds__(256) void presence_only_kernel(
    const float4* __restrict__ lf,
    const float*  __restrict__ W_pres,
    const float*  __restrict__ b_pres,
    float* __restrict__ presence_out)
{
    const int lane = threadIdx.x & 63;
    const int wave = blockIdx.x * 4 + (threadIdx.x >> 6);
    const int sub  = lane >> 2;
    const int q    = lane & 3;
    const int row  = wave * 16 + sub;
    const float4* __restrict__ rowp = lf + (size_t)row * 64 + q;
    const float4* __restrict__ wp   = reinterpret_cast<const float4*>(W_pres) + q;

    float p = 0.f;
    #pragma unroll
    for (int t = 0; t < 16; ++t) p += dot4(rowp[4 * t], wp[4 * t]);
    p += __shfl_xor(p, 1);
    p += __shfl_xor(p, 2);
    if (q == 0) presence_out[row] = p + b_pres[0];
}

__global__ __launch_bounds__(64) void topk_nms_recompute_kernel(
    const float4* __restrict__ lf,
    const float*  __restrict__ W_coords,
    const float*  __restrict__ b_coords,
    const float*  __restrict__ presence,
    float* __restrict__ coords_out,
    float* __restrict__ probs_out,
    float* __restrict__ keep_out)
{
    const int bc   = blockIdx.x;
    const int lane = threadIdx.x;

    __shared__ float s_topv[KK];
    __shared__ int   s_topi[KK];
    __shared__ float s_box[KK][4];

    const float* pres = presence + (size_t)bc * RR;
    float v[4]; int id[4];
    #pragma unroll
    for (int t = 0; t < 4; ++t) {
        const int r = lane + 64 * t;
        id[t] = r;
        v[t]  = (r < RR) ? pres[r] : -1e30f;
    }
    for (int k = 0; k < KK; ++k) {
        float bv = v[0]; int bi = id[0];
        #pragma unroll
        for (int t = 1; t < 4; ++t)
            if (v[t] > bv || (v[t] == bv && id[t] < bi)) { bv = v[t]; bi = id[t]; }
        #pragma unroll
        for (int off = 32; off; off >>= 1) {
            const float ov = __shfl_xor(bv, off);
            const int   oi = __shfl_xor(bi, off);
            if (ov > bv || (ov == bv && oi < bi)) { bv = ov; bi = oi; }
        }
        #pragma unroll
        for (int t = 0; t < 4; ++t)
            if (id[t] == bi) v[t] = -1e30f;
        if (lane == 0) { s_topv[k] = bv; s_topi[k] = bi; }
    }
    __syncthreads();

    const int g  = lane >> 4;
    const int sl = lane & 15;
    float4 wc[4][4];
    #pragma unroll
    for (int o = 0; o < 4; ++o)
        #pragma unroll
        for (int t = 0; t < 4; ++t)
            wc[o][t] = reinterpret_cast<const float4*>(W_coords + o * DD)[sl + 16 * t];

    #pragma unroll
    for (int it = 0; it < KK / 4; ++it) {
        const int k   = it * 4 + g;
        const int row = s_topi[k];
        const float4* __restrict__ rp = lf + ((size_t)bc * RR + row) * 64 + sl;
        float acc[4] = {0.f, 0.f, 0.f, 0.f};
        #pragma unroll
        for (int t = 0; t < 4; ++t) {
            const float4 x = rp[16 * t];
            #pragma unroll
            for (int o = 0; o < 4; ++o)
                acc[o] += x.x * wc[o][t].x + x.y * wc[o][t].y
                        + x.z * wc[o][t].z + x.w * wc[o][t].w;
        }
        #pragma unroll
        for (int off = 8; off; off >>= 1) {
            #pragma unroll
            for (int o = 0; o < 4; ++o) acc[o] += __shfl_xor(acc[o], off);
        }
        if (sl == 0) {
            const int   ix = row % GG, iy = row / GG;
            const float cx = (ix + 0.5f) / (float)GG;
            const float cy = (iy + 0.5f) / (float)GG;
            s_box[k][0] = acc[0] + b_coords[0] + cx;
            s_box[k][1] = acc[1] + b_coords[1] + cy;
            s_box[k][2] = acc[2] + b_coords[2] + cx;
            s_box[k][3] = acc[3] + b_coords[3] + cy;
        }
    }
    __syncthreads();

    float x1 = 0.f, y1 = 0.f, x2 = 0.f, y2 = 0.f, area = 0.f, prob = 0.f;
    int kp = 0;
    if (lane < KK) {
        x1 = s_box[lane][0]; y1 = s_box[lane][1];
        x2 = s_box[lane][2]; y2 = s_box[lane][3];
        area = fmaxf(x2 - x1, 0.f) * fmaxf(y2 - y1, 0.f);
        prob = 1.f / (1.f + expf(-s_topv[lane]));
        kp = (prob > CONF_) ? 1 : 0;
    }
    for (int i = 0; i < KK; ++i) {
        const int   ki  = __shfl(kp, i);
        const float bx1 = __shfl(x1, i), by1 = __shfl(y1, i);
        const float bx2 = __shfl(x2, i), by2 = __shfl(y2, i);
        const float ai  = __shfl(area, i);
        if (lane > i && lane < KK && ki) {
            const float xx1 = fmaxf(x1, bx1), yy1 = fmaxf(y1, by1);
            const float xx2 = fminf(x2, bx2), yy2 = fminf(y2, by2);
            const float inter = fmaxf(xx2 - xx1, 0.f) * fmaxf(yy2 - yy1, 0.f);
            const float uni   = area + ai - inter;
            const float iou   = inter / fmaxf(uni, 1e-9f);
            if (iou > IOU_THR_) kp = 0;
        }
    }
    if (lane < KK) {
        const size_t base = (size_t)bc * KK + lane;
        const float  kf   = kp ? 1.f : 0.f;
        coords_out[base * 4 + 0] = x1 * kf;
        coords_out[base * 4 + 1] = y1 * kf;
        coords_out[base * 4 + 2] = x2 * kf;
        coords_out[base * 4 + 3] = y2 * kf;
        probs_out[base] = prob * kf;
        keep_out[base]  = kf;
    }
}

extern "C" void kernel_launch(void* const* d_in, const int* in_sizes, int n_in,
                              void* d_out, int out_size, void* d_ws, size_t ws_size,
                              hipStream_t stream) {
    const float* lf       = (const float*)d_in[0];
    const float* W_coords = (const float*)d_in[1];
    const float* b_coords = (const float*)d_in[2];
    const float* W_pres   = (const float*)d_in[3];
    const float* b_pres   = (const float*)d_in[4];

    float* out          = (float*)d_out;
    float* coords_out   = out + COORDS_OFF;
    float* probs_out    = out + PROBS_OFF;
    float* keep_out     = out + KEEP_OFF;
    float* presence_out = out + PRES_OFF;

    const size_t ws_needed = (size_t)NROWS * 4 * sizeof(float);

    if (ws_size >= ws_needed) {
        float4* boxes_ws = (float4*)d_ws;
        // Stage 1: 2048 blocks (= exactly 8 waves/SIMD resident), grid-stride.
        mlp_kernel<<<2048, 256, 0, stream>>>(
            (const float4*)lf, W_coords, b_coords, W_pres, b_pres,
            presence_out, boxes_ws);
        // Stage 2: 240 blocks x 4 waves, one wave per (b,c).
        topk_nms_kernel<<<BB * CC / 4, 256, 0, stream>>>(
            presence_out, boxes_ws,
            coords_out, probs_out, keep_out);
    } else {
        presence_only_kernel<<<NROWS / 64, 256, 0, stream>>>(
            (const float4*)lf, W_pres, b_pres, presence_out);
        topk_nms_recompute_kernel<<<BB * CC, 64, 0, stream>>>(
            (const float4*)lf, W_coords, b_coords, presence_out,
            coords_out, probs_out, keep_out);
    }
}

// Round 6
// 50.459 us; speedup vs baseline: 2.1875x; 1.0199x over previous
//
#include <hip/hip_runtime.h>
#include <hip/hip_bf16.h>
#include <math.h>

// Problem constants (from reference)
#define BB 32
#define CC 30
#define RR 196
#define DD 256
#define KK 20
#define GG 14            // sqrt(RR)
#define CONF_ 0.5f
#define IOU_THR_ 0.3f

constexpr int COORDS_OFF = 0;                // (B,C,K,4)
constexpr int PROBS_OFF  = BB * CC * KK * 4; // 76800
constexpr int KEEP_OFF   = PROBS_OFF + BB * CC * KK;  // 96000
constexpr int PRES_OFF   = KEEP_OFF + BB * CC * KK;   // 115200

__device__ __forceinline__ float dot4(float4 a, float4 b) {
    return a.x * b.x + a.y * b.y + a.z * b.z + a.w * b.w;
}

// ---------------------------------------------------------------------------
// ONE kernel, one block per (b,c) tile, 960 blocks x 256 threads.
//   Phase 1 (all 4 waves): stream the tile's 196 rows once with the R4 lean
//     body — 16 lanes/row, 4 rows/granule, all 20 weight float4s pinned in
//     registers (80 VGPR), ONE load instruction per 1 KiB of lf. Wave w owns
//     rows [w*49, w*49+49). Logit+box -> LDS; logit -> d_out presence.
//   Phase 2 (wave 0, after block-local __syncthreads): top-K argmax over the
//     196 LDS logits (sigmoid monotone), boxes from LDS, lockstep NMS,
//     outputs. No d_ws, no second launch, no inter-block communication.
// R2 post-mortem applied: its failure was the 248-VGPR monolithic body
// (2 waves/SIMD, latency-bound), not the per-tile structure. launch_bounds
// (256,4) caps VGPR at 128 -> 4 blocks/CU -> all 960 blocks co-resident.
// #pragma unroll 1 on the granule loop keeps the body tight (no 12x unroll
// register balloon); 15 waves/CU x 4 KiB in flight hides HBM latency (~5x
// the 10.2 B/cy/CU needed to saturate 6.3 TB/s).
// ---------------------------------------------------------------------------
__global__ __launch_bounds__(256, 4) void fused_bbox_lean(
    const float4* __restrict__ lf,        // (B*C*R) x 64 float4
    const float*  __restrict__ W_coords,  // 4 x 256
    const float*  __restrict__ b_coords,  // 4
    const float*  __restrict__ W_pres,    // 256
    const float*  __restrict__ b_pres,    // 1
    float* __restrict__ coords_out,
    float* __restrict__ probs_out,
    float* __restrict__ keep_out,
    float* __restrict__ presence_out)
{
    const int bc   = blockIdx.x;
    const int tid  = threadIdx.x;
    const int wv   = tid >> 6;
    const int lane = tid & 63;
    const int gr   = lane >> 4;   // row slot within granule (0..3)
    const int o    = lane & 15;   // sub-lane within row

    __shared__ float  s_logit[RR];
    __shared__ float4 s_box[RR];

    const float4* __restrict__ Wp4 = reinterpret_cast<const float4*>(W_pres);
    const float4* __restrict__ Wc4 = reinterpret_cast<const float4*>(W_coords);

    // All weights in registers, loaded once (L1-hit), loop-invariant.
    float4 wp[4], w0[4], w1[4], w2[4], w3[4];
    #pragma unroll
    for (int t = 0; t < 4; ++t) {
        wp[t] = Wp4[o + 16 * t];
        w0[t] = Wc4[      o + 16 * t];
        w1[t] = Wc4[ 64 + o + 16 * t];
        w2[t] = Wc4[128 + o + 16 * t];
        w3[t] = Wc4[192 + o + 16 * t];
    }
    const float bp  = b_pres[0];
    const float bc0 = b_coords[0], bc1 = b_coords[1];
    const float bc2 = b_coords[2], bc3 = b_coords[3];

    const size_t tile  = (size_t)bc * RR;
    const int    wbase = wv * 49;         // 4 waves x 49 rows = 196

    // ---- Phase 1: 12 granules of 4 rows ----
    #pragma unroll 1
    for (int j = 0; j < 12; ++j) {
        const int r = wbase + 4 * j + gr;
        const float4* __restrict__ rp = lf + (tile + r) * 64;

        float ap = 0.f, a0 = 0.f, a1 = 0.f, a2 = 0.f, a3 = 0.f;
        #pragma unroll
        for (int t = 0; t < 4; ++t) {
            const float4 x = rp[o + 16 * t];
            ap += dot4(x, wp[t]);
            a0 += dot4(x, w0[t]);
            a1 += dot4(x, w1[t]);
            a2 += dot4(x, w2[t]);
            a3 += dot4(x, w3[t]);
        }
        #pragma unroll
        for (int off = 1; off <= 8; off <<= 1) {
            ap += __shfl_xor(ap, off);
            a0 += __shfl_xor(a0, off);
            a1 += __shfl_xor(a1, off);
            a2 += __shfl_xor(a2, off);
            a3 += __shfl_xor(a3, off);
        }
        if (o == 0) {
            const float lg = ap + bp;
            s_logit[r] = lg;
            presence_out[tile + r] = lg;
            const int   ix = r % GG, iy = r / GG;
            const float cx = (ix + 0.5f) / (float)GG;
            const float cy = (iy + 0.5f) / (float)GG;
            s_box[r] = make_float4(a0 + bc0 + cx, a1 + bc1 + cy,
                                   a2 + bc2 + cx, a3 + bc3 + cy);
        }
    }

    // ---- Phase 1 tail: row wbase+48, lanes 0..15 only ----
    if (gr == 0) {
        const int r = wbase + 48;
        const float4* __restrict__ rp = lf + (tile + r) * 64;
        float ap = 0.f, a0 = 0.f, a1 = 0.f, a2 = 0.f, a3 = 0.f;
        #pragma unroll
        for (int t = 0; t < 4; ++t) {
            const float4 x = rp[o + 16 * t];
            ap += dot4(x, wp[t]);
            a0 += dot4(x, w0[t]);
            a1 += dot4(x, w1[t]);
            a2 += dot4(x, w2[t]);
            a3 += dot4(x, w3[t]);
        }
        #pragma unroll
        for (int off = 1; off <= 8; off <<= 1) {
            ap += __shfl_xor(ap, off);
            a0 += __shfl_xor(a0, off);
            a1 += __shfl_xor(a1, off);
            a2 += __shfl_xor(a2, off);
            a3 += __shfl_xor(a3, off);
        }
        if (o == 0) {
            const float lg = ap + bp;
            s_logit[r] = lg;
            presence_out[tile + r] = lg;
            const int   ix = r % GG, iy = r / GG;
            const float cx = (ix + 0.5f) / (float)GG;
            const float cy = (iy + 0.5f) / (float)GG;
            s_box[r] = make_float4(a0 + bc0 + cx, a1 + bc1 + cy,
                                   a2 + bc2 + cx, a3 + bc3 + cy);
        }
    }

    __syncthreads();
    if (wv != 0) return;

    // ---- Phase 2 (wave 0): top-K argmax over LDS logits ----
    float v[4]; int id[4];
    #pragma unroll
    for (int t = 0; t < 4; ++t) {
        const int r = lane + 64 * t;
        id[t] = r;
        v[t]  = (r < RR) ? s_logit[r] : -1e30f;
    }

    float myv = -1e30f; int myi = 0;
    for (int k = 0; k < KK; ++k) {
        float bv = v[0]; int bi = id[0];
        #pragma unroll
        for (int t = 1; t < 4; ++t)
            if (v[t] > bv || (v[t] == bv && id[t] < bi)) { bv = v[t]; bi = id[t]; }
        #pragma unroll
        for (int off = 32; off; off >>= 1) {
            const float ov = __shfl_xor(bv, off);
            const int   oi = __shfl_xor(bi, off);
            if (ov > bv || (ov == bv && oi < bi)) { bv = ov; bi = oi; }
        }
        #pragma unroll
        for (int t = 0; t < 4; ++t)
            if (id[t] == bi) v[t] = -1e30f;
        if (lane == k) { myv = bv; myi = bi; }
    }

    // ---- box fetch + NMS ----
    float x1 = 0.f, y1 = 0.f, x2 = 0.f, y2 = 0.f, area = 0.f, prob = 0.f;
    int kp = 0;
    if (lane < KK) {
        const float4 b = s_box[myi];
        x1 = b.x; y1 = b.y; x2 = b.z; y2 = b.w;
        area = fmaxf(x2 - x1, 0.f) * fmaxf(y2 - y1, 0.f);
        prob = 1.f / (1.f + expf(-myv));
        kp   = (prob > CONF_) ? 1 : 0;
    }
    for (int i = 0; i < KK; ++i) {
        const int   ki  = __shfl(kp, i);
        const float bx1 = __shfl(x1, i), by1 = __shfl(y1, i);
        const float bx2 = __shfl(x2, i), by2 = __shfl(y2, i);
        const float ai  = __shfl(area, i);
        if (lane > i && lane < KK && ki) {
            const float xx1 = fmaxf(x1, bx1), yy1 = fmaxf(y1, by1);
            const float xx2 = fminf(x2, bx2), yy2 = fminf(y2, by2);
            const float inter = fmaxf(xx2 - xx1, 0.f) * fmaxf(yy2 - yy1, 0.f);
            const float uni   = area + ai - inter;
            const float iou   = inter / fmaxf(uni, 1e-9f);
            if (iou > IOU_THR_) kp = 0;
        }
    }

    // ---- outputs ----
    if (lane < KK) {
        const size_t base = (size_t)bc * KK + lane;
        const float  kf   = kp ? 1.f : 0.f;
        coords_out[base * 4 + 0] = x1 * kf;
        coords_out[base * 4 + 1] = y1 * kf;
        coords_out[base * 4 + 2] = x2 * kf;
        coords_out[base * 4 + 3] = y2 * kf;
        probs_out[base] = prob * kf;
        keep_out[base]  = kf;
    }
}

extern "C" void kernel_launch(void* const* d_in, const int* in_sizes, int n_in,
                              void* d_out, int out_size, void* d_ws, size_t ws_size,
                              hipStream_t stream) {
    const float* lf       = (const float*)d_in[0];
    const float* W_coords = (const float*)d_in[1];
    const float* b_coords = (const float*)d_in[2];
    const float* W_pres   = (const float*)d_in[3];
    const float* b_pres   = (const float*)d_in[4];

    float* out          = (float*)d_out;
    float* coords_out   = out + COORDS_OFF;
    float* probs_out    = out + PROBS_OFF;
    float* keep_out     = out + KEEP_OFF;
    float* presence_out = out + PRES_OFF;

    // One block per (b,c); 960 blocks, fully independent (single launch).
    fused_bbox_lean<<<BB * CC, 256, 0, stream>>>(
        (const float4*)lf, W_coords, b_coords, W_pres, b_pres,
        coords_out, probs_out, keep_out, presence_out);
}